// Round 3
// baseline (248.004 us; speedup 1.0000x reference)
//
#include <hip/hip_runtime.h>
#include <math.h>

#define LL 128
#define TT 11
#define NP 121            // T*T (y, y_prev) pairs
#define KK 7
#define GS 20             // sp group stride (floats); group g at [g*20 .. g*20+10], pad at +11
#define SPW 240           // 11 groups*20 + dummy slots 220..226
#define NSLOT 8           // raw-slice ring slots (panes)

#define LOG2E 1.4426950408889634f
#define LN2   0.6931471805599453f

typedef const __attribute__((address_space(1))) unsigned int* gas_t;
typedef __attribute__((address_space(3)))       unsigned int* las_t;

__device__ __forceinline__ float fast_exp2(float x) { return __builtin_amdgcn_exp2f(x); }
__device__ __forceinline__ float fast_log2(float x) { return __builtin_amdgcn_logf(x); }
#if __has_builtin(__builtin_amdgcn_rcpf)
__device__ __forceinline__ float fast_rcp(float x) { return __builtin_amdgcn_rcpf(x); }
#else
__device__ __forceinline__ float fast_rcp(float x) { return 1.0f / x; }
#endif
__device__ __forceinline__ float rfl(float x) {
    return __int_as_float(__builtin_amdgcn_readfirstlane(__float_as_int(x)));
}
__device__ __forceinline__ void cfence() { __builtin_amdgcn_wave_barrier(); }

// s_waitcnt vmcnt(n) with a compile-time-folded switch (immediate must be literal).
__device__ __forceinline__ void vmwait(int n) {
    switch (n) {
        case 0:  asm volatile("s_waitcnt vmcnt(0)"  ::: "memory"); break;
        case 7:  asm volatile("s_waitcnt vmcnt(7)"  ::: "memory"); break;
        case 14: asm volatile("s_waitcnt vmcnt(14)" ::: "memory"); break;
        case 21: asm volatile("s_waitcnt vmcnt(21)" ::: "memory"); break;
        case 28: asm volatile("s_waitcnt vmcnt(28)" ::: "memory"); break;
        default: break;   // -1: no wait
    }
}

// ---------------------------------------------------------------------------
// Fused semi-CRF forward DP, v2: raw score slices DMA'd straight into an LDS
// ring via global_load_lds (no prep kernel, no E array, no per-lane scattered
// global loads).
//
// Round-2 post-mortem: the register-staged fused kernel converted pane i+2 at
// step i but loaded it at step i-2 -- only ~600 cyc of lead vs ~900 cyc HBM
// latency (GPU nearly idle at 16 waves) => chain-blocking vmcnt stall every
// step. Here the lead is 5 panes (~1500 cyc) and the per-step wait is a
// counted vmcnt(28), so pane i+1's DMA has long retired when we wait.
//
// Layout: for pane p (DP step p), slice k holds scores[b][j][p-1][.][.] with
// j = p-7+k -- 121 contiguous floats. One width-16 global_load_lds per slice
// (7 vmem ops/pane, dest = ring[p&7][k][lane*4floats]). Per-lane source
// offset: lane l<30 -> l*16 bytes; lane 30 -> 468 (stays inside the 484-B
// slice, so nothing ever reads past the scores array even for the final
// slice); lanes >=31 -> 0 (dest garbage, never read). The remap puts slice
// bytes 468..484 at LDS bytes 480..496, so pair index 120 (only lane 56's
// second-half pair) reads LDS word 123 instead of 120.
//
// DP recurrence (identical to the passing rounds, absmax 0):
//   window W[k][yp] = exp2(alpha2[j] - C)
//   phase 1: s(y,yp) = sum_k E_k[y][yp] * W[k][yp]   (7-FMA tree)
//   phase 2: S(y) = sum_yp s(y,yp) via the sp LDS round trip (transpose)
//   rescale: W' = shift(W,S) * rcp(S(0))  -- zero transcendentals on-chain.
// Converts (14 exp2 + mask, pane i+1) are off-chain, overlapping the phase-2
// LDS latency.
// ---------------------------------------------------------------------------
__global__ __launch_bounds__(64, 1) void hscrf_fused2(const float* __restrict__ scores,
                                                      const int* __restrict__ mask,
                                                      float* __restrict__ out,
                                                      int n_batch)
{
    const int l = threadIdx.x;
    const int b = blockIdx.x;
    if (b >= n_batch) return;

    __shared__ __align__(64) float ring[NSLOT][KK][256];   // 56 KB raw-slice ring
    __shared__ __align__(64) float sp[SPW];

    const int o1  = l + 64;
    const int o1c = (o1 < NP) ? o1 : 0;
    const int y0 = l / TT,   yp0 = l % TT;
    const int y1 = o1c / TT, yp1 = o1c % TT;
    const int e0 = yp0 * TT + y0;                         // raw offset, pair 0 (max 115)
    const int e1 = o1c % TT * TT + o1c / TT;              // == yp1*TT + y1
    const int f0 = e0;                                    // e0 < 120 always for l < 64
    const int f1 = (e1 == 120) ? 123 : e1;                // lane 56 remap (see header)
    const int i0w = y0 * GS + yp0;                        // phase-1 write slots
    const int i1w = (o1 < NP) ? (y1 * GS + yp1) : (220 + (l - 57));

    if (l < TT) sp[l * GS + 11] = 0.0f;                   // zero pad slot for b128 phase-2

    const int mb = mask[b];
    const float* sb = scores + (size_t)b * (size_t)(LL * (size_t)LL * NP);

    // Per-lane DMA source byte offset within a 484-B slice (in-bounds by design).
    const int src_off = (l < 30) ? l * 16 : ((l == 30) ? 468 : 0);

    // DMA pane p: 7 slices, one width-16 global_load_lds each.
    auto dma_pane = [&](int p) {
        const int slot = p & (NSLOT - 1);
        const int pi = p - 1;
#pragma unroll
        for (int k = 0; k < KK; ++k) {
            const int j  = p - KK + k;
            const int jc = j < 0 ? 0 : j;                 // clamped; masked at convert
            const float* slice = sb + ((size_t)jc * LL + (size_t)pi) * NP;
            __builtin_amdgcn_global_load_lds(
                (gas_t)((const char*)slice + src_off),
                (las_t)&ring[slot][k][0], 16, 0, 0);
        }
    };

    // Convert pane p from the ring into linear-domain E regs (off-chain).
    auto convert = [&](int p, float (&D0)[KK], float (&D1)[KK]) {
        const int slot = p & (NSLOT - 1);
#pragma unroll
        for (int k = 0; k < KK; ++k) {
            const float r0 = ring[slot][k][f0];
            const float r1 = ring[slot][k][f1];
            const float v0 = fast_exp2(r0 * LOG2E);
            const float v1 = fast_exp2(r1 * LOG2E);
            const bool ok = (p - KK + k) >= 0;            // j<0 mask (uniform compare)
            D0[k] = ok ? v0 : 0.0f;
            D1[k] = ok ? v1 : 0.0f;
        }
    };

    // Linear-domain windows. Row 0: start state (yp==10) = 1, others 0.
    float W0[KK], W1[KK];
#pragma unroll
    for (int k = 0; k < KK; ++k) { W0[k] = 0.0f; W1[k] = 0.0f; }
    W0[KK - 1] = (yp0 == TT - 1) ? 1.0f : 0.0f;
    W1[KK - 1] = (yp1 == TT - 1) ? 1.0f : 0.0f;

    float Cc = 0.0f;       // running log2 scale: alpha2[i][y] = Cc + log2(S_i(y))
    float saved = 0.0f;

    float eX0[KK], eX1[KK], eY0[KK], eY1[KK];   // E ping-pong (odd steps: eX)

    // Prologue: panes 1..5 in flight (35 ops); wait to 28 -> pane 1 complete.
    dma_pane(1); dma_pane(2); dma_pane(3); dma_pane(4); dma_pane(5);
    vmwait(28);
    convert(1, eX0, eX1);                       // E(1) (one-time stall only)

    auto body = [&](int i, bool do_load, int vmw, bool do_conv,
                    float (&EC0)[KK], float (&EC1)[KK],    // E(i) consumed
                    float (&EN0)[KK], float (&EN1)[KK]) {  // E(i+1) produced
        // ---- phase 1: 7 FMAs per pair (tree), sp write ----
        float p0 = fmaf(EC0[0], W0[0], EC0[1] * W0[1]);
        float q0 = fmaf(EC0[2], W0[2], EC0[3] * W0[3]);
        float u0 = fmaf(EC0[4], W0[4], EC0[5] * W0[5]);
        float s0 = (p0 + q0) + fmaf(EC0[6], W0[6], u0);
        float p1 = fmaf(EC1[0], W1[0], EC1[1] * W1[1]);
        float q1 = fmaf(EC1[2], W1[2], EC1[3] * W1[3]);
        float u1 = fmaf(EC1[4], W1[4], EC1[5] * W1[5]);
        float s1 = (p1 + q1) + fmaf(EC1[6], W1[6], u1);
        sp[i0w] = s0;
        sp[i1w] = s1;

        cfence();                      // DS pipe in-order per wave

        // ---- phase 2 reads (chain-critical; issued before the conv reads so
        //      the in-order DS pipe returns them first) ----
        const float4 qa0 = *(const float4*)(sp + yp0 * GS);
        const float4 qb0 = *(const float4*)(sp + yp0 * GS + 4);
        const float4 qc0 = *(const float4*)(sp + yp0 * GS + 8);   // pad=0
        const float4 qa1 = *(const float4*)(sp + yp1 * GS);
        const float4 qb1 = *(const float4*)(sp + yp1 * GS + 4);
        const float4 qc1 = *(const float4*)(sp + yp1 * GS + 8);

        // ---- off-chain: keep the ring full (lead 5), convert pane i+1 ----
        if (do_load) dma_pane(i + 5);
        vmwait(vmw);                   // steady state: vmcnt(28) retires pane i+1,
                                       // issued ~4-5 steps (~1200+ cyc) earlier -> no stall
        if (do_conv) convert(i + 1, EN0, EN1);

        // ---- phase-2 sums ----
        const float SA = (((qa0.x + qa0.y) + (qa0.z + qa0.w)) +
                          ((qb0.x + qb0.y) + (qb0.z + qb0.w))) +
                         ((qc0.x + qc0.y) + (qc0.z + qc0.w));
        const float SB = (((qa1.x + qa1.y) + (qa1.z + qa1.w)) +
                          ((qb1.x + qb1.y) + (qb1.z + qb1.w))) +
                         ((qc1.x + qc1.y) + (qc1.z + qc1.w));

        // ---- rescale: r = 1/S(0) (lane 0 has yp0==0) ----
        const float s0u = rfl(SA);
        const float r = fast_rcp(s0u);

        saved = (i == mb) ? Cc + fast_log2(SA) : saved;   // alpha2[i][yp0], off-chain
        Cc += fast_log2(s0u);                             // off-chain

#pragma unroll
        for (int k = 0; k < KK - 1; ++k) { W0[k] = W0[k + 1] * r; W1[k] = W1[k + 1] * r; }
        W0[KK - 1] = SA * r;
        W1[KK - 1] = SB * r;

        cfence();                      // order phase-2 reads before next sp writes
    };

    // Main loop: steps 1..122 (loads panes 6..127). Odd steps consume eX.
    for (int i = 1; i <= 121; i += 2) {
        body(i,     true, 28, true, eX0, eX1, eY0, eY1);
        body(i + 1, true, 28, true, eY0, eY1, eX0, eX1);
    }
    // Tail: step 123 loads pane 128; then drain with descending counted waits.
    body(123, true,  28, true,  eX0, eX1, eY0, eY1);   // conv 124
    body(124, false, 21, true,  eY0, eY1, eX0, eX1);   // conv 125
    body(125, false, 14, true,  eX0, eX1, eY0, eY1);   // conv 126
    body(126, false,  7, true,  eY0, eY1, eX0, eX1);   // conv 127
    body(127, false,  0, true,  eX0, eX1, eY0, eY1);   // conv 128
    body(128, false, -1, false, eY0, eY1, eX0, eX1);

    if (l == TT - 2) {                 // lane 9: yp0 == stop_id = 9
        atomicAdd(out, saved * LN2);   // back to natural log
    }
}

extern "C" void kernel_launch(void* const* d_in, const int* in_sizes, int n_in,
                              void* d_out, int out_size, void* d_ws, size_t ws_size,
                              hipStream_t stream) {
    const float* scores = (const float*)d_in[0];
    const int*   mask   = (const int*)d_in[1];
    float* out = (float*)d_out;
    const int B = in_sizes[1];   // 16

    hipMemsetAsync(out, 0, sizeof(float) * out_size, stream);

    // Workspace unused (round-1/2 finding: the ws poison fill is unconditional,
    // so using or not using d_ws changes nothing; we simply don't need it).
    (void)d_ws; (void)ws_size;

    hscrf_fused2<<<B, 64, 0, stream>>>(scores, mask, out, B);
}

// Round 4
// 200.710 us; speedup vs baseline: 1.2356x; 1.2356x over previous
//
#include <hip/hip_runtime.h>
#include <math.h>

#define LL 128
#define TT 11
#define NP 121            // T*T (y, y_prev) pairs
#define KK 7
#define GS 20             // sp group stride (floats); group g at [g*20 .. g*20+10], pad at +11
#define SPW 240           // 11 groups*20 + dummy slots 220..226
#define NSLOT 8           // E-pane LDS ring slots
#define PANEF 1024        // floats per E pane: [m=2][pair o=128][float4]

#define LOG2E 1.4426950408889634f
#define LN2   0.6931471805599453f

__device__ __forceinline__ float fast_exp2(float x) { return __builtin_amdgcn_exp2f(x); }
__device__ __forceinline__ float fast_log2(float x) { return __builtin_amdgcn_logf(x); }
#if __has_builtin(__builtin_amdgcn_rcpf)
__device__ __forceinline__ float fast_rcp(float x) { return __builtin_amdgcn_rcpf(x); }
#else
__device__ __forceinline__ float fast_rcp(float x) { return 1.0f / x; }
#endif
__device__ __forceinline__ float rfl(float x) {
    return __int_as_float(__builtin_amdgcn_readfirstlane(__float_as_int(x)));
}
__device__ __forceinline__ void cfence() { __builtin_amdgcn_wave_barrier(); }
#define VMWAIT28() asm volatile("s_waitcnt vmcnt(28)" ::: "memory")
#define VMWAIT0()  asm volatile("s_waitcnt vmcnt(0)"  ::: "memory")
#define LGKM0()    asm volatile("s_waitcnt lgkmcnt(0)" ::: "memory")

// Compile-time-fenced workgroup barrier (s_barrier intrinsic alone is not a
// compiler memory fence; empty asm blocks compile-time reordering of LDS ops).
__device__ __forceinline__ void block_sync() {
    asm volatile("" ::: "memory");
    __builtin_amdgcn_s_barrier();
    asm volatile("" ::: "memory");
}

// ---------------------------------------------------------------------------
// Producer/consumer fused semi-CRF forward DP.
//
// Round-3 post-mortem: the single-wave fused kernel ran at 101 us (1890
// cyc/step) with FETCH=512B replays at identical time -- pure issue/latency
// bound: 14 exp2 + 14 conflicted ds_read + 7 DMA per step all serialize with
// the chain (1 wave/SIMD, nothing hides anything), and the convert's
// conflicted reads queue ahead of the chain-critical transpose reads in the
// in-order DS pipe (163K conflict cycles).
//
// Fix: 2 waves/block on separate SIMDs of one CU.
//   wave 0 (consumer): EXACT round-0/1 dp body minus all DMA -- per step:
//     16 FMA -> sp write -> cfence -> 6x b128 transpose reads -> sums ->
//     rcp rescale (zero transcendentals on-chain) + 4x conflict-free b128
//     next-E reads. ~350-450 cyc/step target.
//   wave 1 (producer): for each pane p: 14 per-lane gather loads of raw
//     scores (lead 2 ticks, counted vmcnt(28)), 14 exp2 + j<0/o>=121 masking
//     (bit-identical to the old prep kernel), 4x stride-16 ds_write_b128
//     into the split-pane ring layout the consumer reads. lgkmcnt(0) before
//     each barrier publishes the writes.
// Sync: one s_barrier per tick (= 2 DP steps). Producer stays 2 ticks ahead;
// ring holds 8 panes (6 live: consumer i..i+1(+prefetch i+2), ready +2,
// producer writing +2). Ring slot of pane p = p & 7.
//
// Tick schedule (producer): prologue converts panes 1..4, issues 5..8;
// tick t in 1..60: issue panes 2t+5,2t+6; vmwait(28); convert 2t+3,2t+4.
// Tick 61: issue 127,128; vmwait(28); convert 125,126. Tick 62: vmwait(0);
// convert 127,128. Ticks 63,64: barrier only. 65 barriers each side.
// ---------------------------------------------------------------------------
__global__ __launch_bounds__(128, 1) void hscrf_pc(const float* __restrict__ scores,
                                                   const int* __restrict__ mask,
                                                   float* __restrict__ out,
                                                   int n_batch)
{
    const int tid = threadIdx.x;
    const int l   = tid & 63;
    const int wid = tid >> 6;
    const int b   = blockIdx.x;
    if (b >= n_batch) return;

    __shared__ __align__(64) float ring[NSLOT][PANEF];   // 32 KB
    __shared__ __align__(64) float sp[SPW];

    const float* sb = scores + (size_t)b * (size_t)(LL * (size_t)LL * NP);

    if (wid == 1) {
        // ================= PRODUCER =================
        const int o1  = l + 64;
        const bool v1 = (o1 < NP);
        const int o1c = v1 ? o1 : 0;
        const int e0 = (l % TT) * TT + (l / TT);          // transposed slice offset
        const int e1 = (o1c % TT) * TT + (o1c / TT);

        // Two ping-pong buffers, each holding 2 panes x 2 pairs x 7 raw floats.
        float XA0[KK], XA1[KK], XB0[KK], XB1[KK];
        float YA0[KK], YA1[KK], YB0[KK], YB1[KK];

        // Issue gather loads for panes p and p+1 (14 per lane per pane).
        auto issue2 = [&](int p, float (&a0)[KK], float (&a1)[KK],
                          float (&c0)[KK], float (&c1)[KK]) {
#pragma unroll
            for (int k = 0; k < KK; ++k) {
                const int j = p - KK + k; const int jc = j < 0 ? 0 : j;
                const float* s0 = sb + ((size_t)jc * LL + (size_t)(p - 1)) * NP;
                a0[k] = s0[e0]; a1[k] = s0[e1];
            }
#pragma unroll
            for (int k = 0; k < KK; ++k) {
                const int j = p + 1 - KK + k; const int jc = j < 0 ? 0 : j;
                const float* s1 = sb + ((size_t)jc * LL + (size_t)p) * NP;
                c0[k] = s1[e0]; c1[k] = s1[e1];
            }
        };

        // Convert one pane to linear domain and publish to the ring
        // (split-pane layout; 4x stride-16 ds_write_b128, conflict-free).
        auto conv1 = [&](int p, const float (&a0)[KK], const float (&a1)[KK]) {
            const int slot = p & (NSLOT - 1);
            float v0[8], v1[8];
#pragma unroll
            for (int k = 0; k < KK; ++k) {
                const bool ok = (p - KK + k) >= 0;        // j >= 0 mask
                const float t0 = fast_exp2(a0[k] * LOG2E);
                const float t1 = fast_exp2(a1[k] * LOG2E);
                v0[k] = ok ? t0 : 0.0f;
                v1[k] = (ok && v1) ? t1 : 0.0f;           // o>=121 pairs -> 0 (as prep)
            }
            v0[7] = 0.0f; v1[7] = 0.0f;
            float4* dst = (float4*)&ring[slot][0];
            dst[l]       = make_float4(v0[0], v0[1], v0[2], v0[3]);
            dst[128 + l] = make_float4(v0[4], v0[5], v0[6], v0[7]);
            dst[64 + l]  = make_float4(v1[0], v1[1], v1[2], v1[3]);
            dst[192 + l] = make_float4(v1[4], v1[5], v1[6], v1[7]);
        };

        // Prologue: convert panes 1..4, leave 5..8 in flight.
        issue2(1, XA0, XA1, XB0, XB1);                    // panes 1,2 -> X
        issue2(3, YA0, YA1, YB0, YB1);                    // panes 3,4 -> Y (56 out)
        VMWAIT28();                                       // X ready
        conv1(1, XA0, XA1); conv1(2, XB0, XB1);
        issue2(5, XA0, XA1, XB0, XB1);                    // panes 5,6 -> X (56 out)
        VMWAIT28();                                       // Y ready
        conv1(3, YA0, YA1); conv1(4, YB0, YB1);
        LGKM0(); block_sync();                            // B0

        // Ticks 1..60 (pairs of odd/even).
        for (int t = 1; t <= 59; t += 2) {
            // odd tick t: issue -> Y, convert X (panes 2t+3, 2t+4)
            issue2(2 * t + 5, YA0, YA1, YB0, YB1);
            VMWAIT28();
            conv1(2 * t + 3, XA0, XA1); conv1(2 * t + 4, XB0, XB1);
            LGKM0(); block_sync();
            // even tick t+1: issue -> X, convert Y
            issue2(2 * t + 7, XA0, XA1, XB0, XB1);
            VMWAIT28();
            conv1(2 * t + 5, YA0, YA1); conv1(2 * t + 6, YB0, YB1);
            LGKM0(); block_sync();
        }
        // Tick 61: issue panes 127,128 -> Y; convert X (125,126).
        issue2(127, YA0, YA1, YB0, YB1);
        VMWAIT28();
        conv1(125, XA0, XA1); conv1(126, XB0, XB1);
        LGKM0(); block_sync();
        // Tick 62: drain; convert Y (127,128).
        VMWAIT0();
        conv1(127, YA0, YA1); conv1(128, YB0, YB1);
        LGKM0(); block_sync();
        // Ticks 63,64: idle.
        block_sync();
        block_sync();
    } else {
        // ================= CONSUMER (dp body, DMA-free) =================
        const int o1  = l + 64;
        const int o1c = (o1 < NP) ? o1 : 0;
        const int y0 = l / TT,   yp0 = l % TT;
        const int y1 = o1c / TT, yp1 = o1c % TT;
        const int i0w = y0 * GS + yp0;
        const int i1w = (o1 < NP) ? (y1 * GS + yp1) : (220 + (l - 57));

        if (l < TT) sp[l * GS + 11] = 0.0f;               // zero pad for b128 phase-2

        const int mb = mask[b];

        float W0[KK], W1[KK];
#pragma unroll
        for (int k = 0; k < KK; ++k) { W0[k] = 0.0f; W1[k] = 0.0f; }
        W0[KK - 1] = (yp0 == TT - 1) ? 1.0f : 0.0f;
        W1[KK - 1] = (yp1 == TT - 1) ? 1.0f : 0.0f;

        float Cc = 0.0f;
        float saved = 0.0f;

        block_sync();                                     // B0: panes 1..4 ready

        const float4* ep1 = (const float4*)&ring[1][0];
        float4 ea0 = ep1[l],      ea1 = ep1[128 + l];
        float4 eb0 = ep1[64 + l], eb1 = ep1[192 + l];

        auto body = [&](int i) {
            // ---- phase 1: 7 FMAs per pair (tree), sp write ----
            float p0 = fmaf(ea0.x, W0[0], ea0.y * W0[1]);
            float q0 = fmaf(ea0.z, W0[2], ea0.w * W0[3]);
            float u0 = fmaf(ea1.x, W0[4], ea1.y * W0[5]);
            float s0 = (p0 + q0) + fmaf(ea1.z, W0[6], u0);
            float p1 = fmaf(eb0.x, W1[0], eb0.y * W1[1]);
            float q1 = fmaf(eb0.z, W1[2], eb0.w * W1[3]);
            float u1 = fmaf(eb1.x, W1[4], eb1.y * W1[5]);
            float s1 = (p1 + q1) + fmaf(eb1.z, W1[6], u1);
            sp[i0w] = s0;
            sp[i1w] = s1;

            cfence();                  // DS pipe in-order per wave

            // ---- phase 2 reads (chain-critical; issued first) ----
            const float4 qa0 = *(const float4*)(sp + yp0 * GS);
            const float4 qb0 = *(const float4*)(sp + yp0 * GS + 4);
            const float4 qc0 = *(const float4*)(sp + yp0 * GS + 8);
            const float4 qa1 = *(const float4*)(sp + yp1 * GS);
            const float4 qb1 = *(const float4*)(sp + yp1 * GS + 4);
            const float4 qc1 = *(const float4*)(sp + yp1 * GS + 8);

            // ---- next-E prefetch (pane i+1; stable, written >=1 tick ago) ----
            const int ns = (i + 1) & (NSLOT - 1);
            const float4* ep = (const float4*)&ring[ns][0];
            const float4 na0 = ep[l],      na1 = ep[128 + l];
            const float4 nb0 = ep[64 + l], nb1 = ep[192 + l];

            // ---- phase-2 sums ----
            const float SA = (((qa0.x + qa0.y) + (qa0.z + qa0.w)) +
                              ((qb0.x + qb0.y) + (qb0.z + qb0.w))) +
                             ((qc0.x + qc0.y) + (qc0.z + qc0.w));
            const float SB = (((qa1.x + qa1.y) + (qa1.z + qa1.w)) +
                              ((qb1.x + qb1.y) + (qb1.z + qb1.w))) +
                             ((qc1.x + qc1.y) + (qc1.z + qc1.w));

            // ---- rescale: r = 1/S(0) ----
            const float s0u = rfl(SA);
            const float r = fast_rcp(s0u);

            saved = (i == mb) ? Cc + fast_log2(SA) : saved;   // off-chain
            Cc += fast_log2(s0u);                             // off-chain

#pragma unroll
            for (int k = 0; k < KK - 1; ++k) { W0[k] = W0[k + 1] * r; W1[k] = W1[k + 1] * r; }
            W0[KK - 1] = SA * r;
            W1[KK - 1] = SB * r;

            ea0 = na0; ea1 = na1; eb0 = nb0; eb1 = nb1;

            cfence();                  // order phase-2 reads before next sp writes
        };

        for (int i = 1; i <= LL; i += 2) {
            body(i);
            body(i + 1);
            block_sync();              // 64 tick barriers
        }

        if (l == TT - 2) {             // lane 9: yp0 == stop_id = 9
            atomicAdd(out, saved * LN2);
        }
    }
}

extern "C" void kernel_launch(void* const* d_in, const int* in_sizes, int n_in,
                              void* d_out, int out_size, void* d_ws, size_t ws_size,
                              hipStream_t stream) {
    const float* scores = (const float*)d_in[0];
    const int*   mask   = (const int*)d_in[1];
    float* out = (float*)d_out;
    const int B = in_sizes[1];   // 16

    hipMemsetAsync(out, 0, sizeof(float) * out_size, stream);

    (void)d_ws; (void)ws_size;   // unused (ws poison is unconditional harness cost)

    hscrf_pc<<<B, 128, 0, stream>>>(scores, mask, out, B);
}

// Round 5
// 185.138 us; speedup vs baseline: 1.3396x; 1.0841x over previous
//
#include <hip/hip_runtime.h>
#include <math.h>

#define LL 128
#define TT 11
#define NP 121            // T*T (y, y_prev) pairs
#define KK 7
#define GS 20             // sp group stride (floats); group g at [g*20 .. g*20+10], pad at +11
#define SPW 240           // 11 groups*20 + dummy slots 220..226
#define NSLOT 8           // E-pane LDS ring slots
#define PANEF 1024        // floats per E pane: [m=2][pair o=128][float4]

#define LOG2E 1.4426950408889634f
#define LN2   0.6931471805599453f

__device__ __forceinline__ float fast_exp2(float x) { return __builtin_amdgcn_exp2f(x); }
__device__ __forceinline__ float fast_log2(float x) { return __builtin_amdgcn_logf(x); }
#if __has_builtin(__builtin_amdgcn_rcpf)
__device__ __forceinline__ float fast_rcp(float x) { return __builtin_amdgcn_rcpf(x); }
#else
__device__ __forceinline__ float fast_rcp(float x) { return 1.0f / x; }
#endif
__device__ __forceinline__ float rfl(float x) {
    return __int_as_float(__builtin_amdgcn_readfirstlane(__float_as_int(x)));
}
__device__ __forceinline__ void cfence() { __builtin_amdgcn_wave_barrier(); }
#define VMWAIT28() asm volatile("s_waitcnt vmcnt(28)" ::: "memory")
#define VMWAIT14() asm volatile("s_waitcnt vmcnt(14)" ::: "memory")
#define VMWAIT0()  asm volatile("s_waitcnt vmcnt(0)"  ::: "memory")
#define LGKM0()    asm volatile("s_waitcnt lgkmcnt(0)" ::: "memory")

__device__ __forceinline__ void block_sync() {
    asm volatile("" ::: "memory");
    __builtin_amdgcn_s_barrier();
    asm volatile("" ::: "memory");
}

// ---------------------------------------------------------------------------
// Producer/consumer semi-CRF forward DP, v2 (3 waves/block).
//
// Round-4 post-mortem: ticks were producer-bound (~2000 cyc): one producer
// wave per tick did 28 SCATTERED gathers (transposed offsets -> ~8 cache
// lines per wave-load), 28 exp2, 8 LDS writes, with only 1 tick of load lead
// on the vmcnt(28). Fixes here:
//   (1) lane->pair relabeling o = yp*11+y makes the gather offset == o:
//       lane l loads slice[l] / slice[l+64] -- fully coalesced 256-B loads.
//       The consumer is the same machine under this relabeling: write slot
//       y*GS+yp, phase-2 read of group yp (= window row), lane 0 still holds
//       S(0); only decode formulas swap and the final readout moves to the
//       lane holding row 9 (pair o1=99 -> lane 35, via SB).
//   (2) TWO producer waves: wave1 odd panes, wave2 even panes (half work).
//   (3) 2-tick load lead, 3-deep buffer rotation (statically unrolled x3),
//       steady-state vmcnt(28) per producer wave -> no load stall.
//
// Tick = 2 DP steps, one s_barrier per tick (65 barriers per wave incl. B0).
// Producer wave w (pw=wid-1) at tick t: issue pane 2t+7+pw (for tick t+2),
// vmcnt(28) retires pane 2t+3+pw (issued at t-2), convert it (14 exp2 +
// masking, bit-identical to prior rounds), publish via 4x stride-16
// ds_write_b128 (conflict-free), lgkmcnt(0), barrier.
// Ring slot of pane p = p&7; consumer at tick t touches panes 2t-1..2t+1,
// producers write 2t+3/2t+4 -- disjoint mod 8.
// ---------------------------------------------------------------------------
__global__ __launch_bounds__(192, 1) void hscrf_pc2(const float* __restrict__ scores,
                                                    const int* __restrict__ mask,
                                                    float* __restrict__ out,
                                                    int n_batch)
{
    const int tid = threadIdx.x;
    const int l   = tid & 63;
    const int wid = tid >> 6;
    const int b   = blockIdx.x;
    if (b >= n_batch) return;

    __shared__ __align__(64) float ring[NSLOT][PANEF];   // 32 KB
    __shared__ __align__(64) float sp[SPW];

    const float* sb = scores + (size_t)b * (size_t)(LL * (size_t)LL * NP);

    const int o1  = l + 64;
    const bool val1 = (o1 < NP);
    const int o1c = val1 ? o1 : 0;

    if (wid >= 1) {
        // ================= PRODUCERS (wave1: odd panes, wave2: even) =========
        const int pw = wid - 1;

        // 3-deep rotation buffers (static names; no runtime indexing).
        float A0[KK], A1[KK], B0[KK], B1[KK], C0[KK], C1[KK];

        // Coalesced: pair o's raw score sits at slice[o] (o = yp*11+y).
        auto issue_pane = [&](int p, float (&a0)[KK], float (&a1)[KK]) {
#pragma unroll
            for (int k = 0; k < KK; ++k) {
                const int j = p - KK + k; const int jc = j < 0 ? 0 : j;
                const float* sl = sb + ((size_t)jc * LL + (size_t)(p - 1)) * NP;
                a0[k] = sl[l];                            // pairs 0..63
                a1[k] = sl[o1c];                          // pairs 64..120 (+clamped dummies)
            }
        };

        // Convert pane p to linear domain, publish to ring (split-pane layout).
        auto conv1 = [&](int p, const float (&a0)[KK], const float (&a1)[KK]) {
            const int slot = p & (NSLOT - 1);
            float v0[8], w1[8];
#pragma unroll
            for (int k = 0; k < KK; ++k) {
                const bool ok = (p - KK + k) >= 0;        // j >= 0 mask
                const float t0 = fast_exp2(a0[k] * LOG2E);
                const float t1 = fast_exp2(a1[k] * LOG2E);
                v0[k] = ok ? t0 : 0.0f;
                w1[k] = (ok && val1) ? t1 : 0.0f;         // o>=121 pairs -> 0
            }
            v0[7] = 0.0f; w1[7] = 0.0f;
            float4* dst = (float4*)&ring[slot][0];
            dst[l]       = make_float4(v0[0], v0[1], v0[2], v0[3]);
            dst[128 + l] = make_float4(v0[4], v0[5], v0[6], v0[7]);
            dst[64 + l]  = make_float4(w1[0], w1[1], w1[2], w1[3]);
            dst[192 + l] = make_float4(w1[4], w1[5], w1[6], w1[7]);
        };

        // Prologue: publish panes {1,3}+pw; leave {5,7}+pw in flight.
        issue_pane(1 + pw, A0, A1);
        issue_pane(3 + pw, B0, B1);
        VMWAIT0();                                        // one-time stall
        conv1(1 + pw, A0, A1);
        conv1(3 + pw, B0, B1);
        issue_pane(5 + pw, B0, B1);                       // tick-1 convert source
        issue_pane(7 + pw, C0, C1);                       // tick-2 convert source
        LGKM0(); block_sync();                            // B0: panes 1..4 live

        // Ticks 1..60: issue pane 2t+7+pw, retire+convert pane 2t+3+pw.
        // Buffer roles rotate with period 3 (t%3 = 1,2,0 -> conv B,C,A).
        for (int t = 1; t <= 58; t += 3) {
            issue_pane(2 * t + 7 + pw, A0, A1);
            VMWAIT28();
            conv1(2 * t + 3 + pw, B0, B1);
            LGKM0(); block_sync();

            issue_pane(2 * t + 9 + pw, B0, B1);
            VMWAIT28();
            conv1(2 * t + 5 + pw, C0, C1);
            LGKM0(); block_sync();

            issue_pane(2 * t + 11 + pw, C0, C1);
            VMWAIT28();
            conv1(2 * t + 7 + pw, A0, A1);
            LGKM0(); block_sync();
        }
        // Tick 61: no issue; retire pane 125+pw (in B).
        VMWAIT14();
        conv1(125 + pw, B0, B1);
        LGKM0(); block_sync();
        // Tick 62: drain; convert pane 127+pw (in C).
        VMWAIT0();
        conv1(127 + pw, C0, C1);
        LGKM0(); block_sync();
        // Ticks 63, 64: idle.
        block_sync();
        block_sync();
    } else {
        // ================= CONSUMER (pure DP chain) ==========================
        // Relabeled decode: pair o = yp*11 + y.
        const int y0 = l % TT,   yp0 = l / TT;
        const int y1 = o1c % TT, yp1 = o1c / TT;
        const int i0w = y0 * GS + yp0;                    // group y, position yp
        const int i1w = val1 ? (y1 * GS + yp1) : (220 + (l - 57));

        if (l < TT) sp[l * GS + 11] = 0.0f;               // zero pad for b128 phase-2

        const int mb = mask[b];

        // Window W[k] = exp2(alpha2[j][row] - Cc), row = lane's yp.
        // Start state: row 10 = 0.0 (linear 1.0), others NEG (linear 0).
        float W0[KK], W1[KK];
#pragma unroll
        for (int k = 0; k < KK; ++k) { W0[k] = 0.0f; W1[k] = 0.0f; }
        W0[KK - 1] = (yp0 == TT - 1) ? 1.0f : 0.0f;       // never for l<64 (yp0<=5)
        W1[KK - 1] = (val1 && yp1 == TT - 1) ? 1.0f : 0.0f;

        float Cc = 0.0f;
        float saved = 0.0f;

        block_sync();                                     // B0: panes 1..4 ready

        const float4* ep1 = (const float4*)&ring[1][0];
        float4 ea0 = ep1[l],      ea1 = ep1[128 + l];
        float4 eb0 = ep1[64 + l], eb1 = ep1[192 + l];

        auto body = [&](int i) {
            // ---- phase 1: 7 FMAs per pair (tree), sp write ----
            float p0 = fmaf(ea0.x, W0[0], ea0.y * W0[1]);
            float q0 = fmaf(ea0.z, W0[2], ea0.w * W0[3]);
            float u0 = fmaf(ea1.x, W0[4], ea1.y * W0[5]);
            float s0 = (p0 + q0) + fmaf(ea1.z, W0[6], u0);
            float p1 = fmaf(eb0.x, W1[0], eb0.y * W1[1]);
            float q1 = fmaf(eb0.z, W1[2], eb0.w * W1[3]);
            float u1 = fmaf(eb1.x, W1[4], eb1.y * W1[5]);
            float s1 = (p1 + q1) + fmaf(eb1.z, W1[6], u1);
            sp[i0w] = s0;
            sp[i1w] = s1;

            cfence();                  // DS pipe in-order per wave

            // ---- phase 2 reads (chain-critical; group yp = window row) ----
            const float4 qa0 = *(const float4*)(sp + yp0 * GS);
            const float4 qb0 = *(const float4*)(sp + yp0 * GS + 4);
            const float4 qc0 = *(const float4*)(sp + yp0 * GS + 8);
            const float4 qa1 = *(const float4*)(sp + yp1 * GS);
            const float4 qb1 = *(const float4*)(sp + yp1 * GS + 4);
            const float4 qc1 = *(const float4*)(sp + yp1 * GS + 8);

            // ---- next-E prefetch (pane i+1; published >=1 tick ago) ----
            const int ns = (i + 1) & (NSLOT - 1);
            const float4* ep = (const float4*)&ring[ns][0];
            const float4 na0 = ep[l],      na1 = ep[128 + l];
            const float4 nb0 = ep[64 + l], nb1 = ep[192 + l];

            // ---- phase-2 sums: SA = S(yp0), SB = S(yp1) ----
            const float SA = (((qa0.x + qa0.y) + (qa0.z + qa0.w)) +
                              ((qb0.x + qb0.y) + (qb0.z + qb0.w))) +
                             ((qc0.x + qc0.y) + (qc0.z + qc0.w));
            const float SB = (((qa1.x + qa1.y) + (qa1.z + qa1.w)) +
                              ((qb1.x + qb1.y) + (qb1.z + qb1.w))) +
                             ((qc1.x + qc1.y) + (qc1.z + qc1.w));

            // ---- rescale: r = 1/S(0) (lane 0: yp0 == 0) ----
            const float s0u = rfl(SA);
            const float r = fast_rcp(s0u);

            // alpha2[i][row 9] lives in SB of lanes with yp1==9 (lane 35).
            saved = (i == mb) ? Cc + fast_log2(SB) : saved;   // off-chain
            Cc += fast_log2(s0u);                             // off-chain

#pragma unroll
            for (int k = 0; k < KK - 1; ++k) { W0[k] = W0[k + 1] * r; W1[k] = W1[k + 1] * r; }
            W0[KK - 1] = SA * r;
            W1[KK - 1] = SB * r;

            ea0 = na0; ea1 = na1; eb0 = nb0; eb1 = nb1;

            cfence();                  // order phase-2 reads before next sp writes
        };

        for (int i = 1; i <= LL; i += 2) {
            body(i);
            body(i + 1);
            block_sync();              // 64 tick barriers
        }

        if (l == 35) {                 // o1 = 99 -> (yp1=9, y1=0): row 9 = stop_id
            atomicAdd(out, saved * LN2);
        }
    }
}

extern "C" void kernel_launch(void* const* d_in, const int* in_sizes, int n_in,
                              void* d_out, int out_size, void* d_ws, size_t ws_size,
                              hipStream_t stream) {
    const float* scores = (const float*)d_in[0];
    const int*   mask   = (const int*)d_in[1];
    float* out = (float*)d_out;
    const int B = in_sizes[1];   // 16

    hipMemsetAsync(out, 0, sizeof(float) * out_size, stream);

    (void)d_ws; (void)ws_size;   // unused (ws poison is unconditional harness cost)

    hscrf_pc2<<<B, 192, 0, stream>>>(scores, mask, out, B);
}

// Round 6
// 177.559 us; speedup vs baseline: 1.3967x; 1.0427x over previous
//
#include <hip/hip_runtime.h>
#include <math.h>

#define LL 128
#define TT 11
#define NP 121            // T*T (y, y_prev) pairs
#define KK 7
#define GS 20             // sp group stride (floats); group g at [g*20 .. g*20+10], pad at +11
#define SPW 240           // 11 groups*20 + dummy slots 220..226
#define NSLOT 8           // E-pane LDS ring slots
#define PANEF 1024        // floats per E pane: [m=2][pair o=128][float4]

#define LOG2E 1.4426950408889634f
#define LN2   0.6931471805599453f

__device__ __forceinline__ float fast_exp2(float x) { return __builtin_amdgcn_exp2f(x); }
__device__ __forceinline__ float fast_log2(float x) { return __builtin_amdgcn_logf(x); }
#if __has_builtin(__builtin_amdgcn_rcpf)
__device__ __forceinline__ float fast_rcp(float x) { return __builtin_amdgcn_rcpf(x); }
#else
__device__ __forceinline__ float fast_rcp(float x) { return 1.0f / x; }
#endif
__device__ __forceinline__ float rfl(float x) {
    return __int_as_float(__builtin_amdgcn_readfirstlane(__float_as_int(x)));
}
__device__ __forceinline__ void cfence() { __builtin_amdgcn_wave_barrier(); }
#define VMWAIT28() asm volatile("s_waitcnt vmcnt(28)" ::: "memory")
#define VMWAIT0()  asm volatile("s_waitcnt vmcnt(0)"  ::: "memory")
#define LGKM0()    asm volatile("s_waitcnt lgkmcnt(0)" ::: "memory")

__device__ __forceinline__ void block_sync() {
    asm volatile("" ::: "memory");
    __builtin_amdgcn_s_barrier();
    asm volatile("" ::: "memory");
}

// ---------------------------------------------------------------------------
// Producer/consumer semi-CRF forward DP, v3: 4 DP steps per tick (32 ticks).
//
// Round-5 post-mortem: ticks (2 steps) ran ~1425 cyc vs ~700 intrinsic.
// Residual attributed to sync structure: 64 on-chain barriers, producer
// ds_writes landing mid-tick on the shared DS pipe ahead of the consumer's
// chain-critical sp round-trip, and per-step next-E prefetch reads queueing
// ahead of the next step's sp writes (in-order DS stream per wave).
//
// v3 changes (per-step math bit-identical to rounds 0-5):
//   (1) 4 steps/tick, 32 ticks: half the barriers, half the interference
//       windows. Consumer tick t consumes panes 4t-3..4t; producers publish
//       panes 4t+1..4t+4 during tick t (ring slots disjoint mod 8).
//   (2) Consumer batches E into registers at tick start (panes p0,p0+1 right
//       after the barrier; panes p0+2,p0+3 after step 1) -- no DS reads
//       between a step's sp writes and its phase-2 reads except the 6
//       phase-2 reads themselves.
//   (3) Producers: 2 waves (odd/even panes), 2 panes per wave per tick,
//       2-buffer rotation, 1-tick load lead (28 outstanding, vmcnt(28);
//       lead ~1300 cyc > HBM latency; scores are L3-resident when warm).
//   (4) Consumer wave runs at s_setprio(1).
//   (5) saved = snapshot(SB, Cc) at i==mb via cndmask; single log2 at end.
// ---------------------------------------------------------------------------
__global__ __launch_bounds__(192, 1) void hscrf_pc3(const float* __restrict__ scores,
                                                    const int* __restrict__ mask,
                                                    float* __restrict__ out,
                                                    int n_batch)
{
    const int tid = threadIdx.x;
    const int l   = tid & 63;
    const int wid = tid >> 6;
    const int b   = blockIdx.x;
    if (b >= n_batch) return;

    __shared__ __align__(64) float ring[NSLOT][PANEF];   // 32 KB
    __shared__ __align__(64) float sp[SPW];

    const float* sb = scores + (size_t)b * (size_t)(LL * (size_t)LL * NP);

    const int o1  = l + 64;
    const bool val1 = (o1 < NP);
    const int o1c = val1 ? o1 : 0;

    if (wid >= 1) {
        // ============ PRODUCERS (wave1: odd panes, wave2: even panes) ========
        const int pw = wid - 1;

        // Two rotation buffers, each holding 2 panes (base, base+2) x 2 halves.
        float Xa0[KK], Xa1[KK], Xb0[KK], Xb1[KK];
        float Ya0[KK], Ya1[KK], Yb0[KK], Yb1[KK];

        // Coalesced gathers: pair o's raw score sits at slice[o] (o = yp*11+y).
        auto issue_pane = [&](int p, float (&a0)[KK], float (&a1)[KK]) {
#pragma unroll
            for (int k = 0; k < KK; ++k) {
                const int j = p - KK + k; const int jc = j < 0 ? 0 : j;
                const float* sl = sb + ((size_t)jc * LL + (size_t)(p - 1)) * NP;
                a0[k] = sl[l];                            // pairs 0..63
                a1[k] = sl[o1c];                          // pairs 64..120
            }
        };
        auto issue_pair = [&](int base, float (&a0)[KK], float (&a1)[KK],
                              float (&b0)[KK], float (&b1)[KK]) {
            issue_pane(base,     a0, a1);                 // 14 loads
            issue_pane(base + 2, b0, b1);                 // 14 loads
        };

        // Convert pane p to linear domain, publish to ring (split-pane layout,
        // 4x stride-16 ds_write_b128, conflict-free). Bit-identical masking.
        auto conv1 = [&](int p, const float (&a0)[KK], const float (&a1)[KK]) {
            const int slot = p & (NSLOT - 1);
            float v0[8], w1[8];
#pragma unroll
            for (int k = 0; k < KK; ++k) {
                const bool ok = (p - KK + k) >= 0;        // j >= 0 mask
                const float t0 = fast_exp2(a0[k] * LOG2E);
                const float t1 = fast_exp2(a1[k] * LOG2E);
                v0[k] = ok ? t0 : 0.0f;
                w1[k] = (ok && val1) ? t1 : 0.0f;         // o>=121 pairs -> 0
            }
            v0[7] = 0.0f; w1[7] = 0.0f;
            float4* dst = (float4*)&ring[slot][0];
            dst[l]       = make_float4(v0[0], v0[1], v0[2], v0[3]);
            dst[128 + l] = make_float4(v0[4], v0[5], v0[6], v0[7]);
            dst[64 + l]  = make_float4(w1[0], w1[1], w1[2], w1[3]);
            dst[192 + l] = make_float4(w1[4], w1[5], w1[6], w1[7]);
        };
        auto conv_pair = [&](int base, const float (&a0)[KK], const float (&a1)[KK],
                             const float (&b0)[KK], const float (&b1)[KK]) {
            conv1(base,     a0, a1);
            conv1(base + 2, b0, b1);
        };

        // Prologue: publish panes 1..4; leave panes 5..8 in flight (buf X).
        issue_pair(1 + pw, Xa0, Xa1, Xb0, Xb1);           // panes 1+pw, 3+pw
        VMWAIT0();                                        // one-time stall
        conv_pair(1 + pw, Xa0, Xa1, Xb0, Xb1);
        issue_pair(5 + pw, Xa0, Xa1, Xb0, Xb1);           // panes 5+pw, 7+pw -> X
        LGKM0(); block_sync();                            // B0: panes 1..4 live

        // Ticks 1..30 issue; conv at tick t = panes {4t+1,4t+3}+pw (issued t-1).
        // Odd tick: issue->Y, conv X.  Even tick: issue->X, conv Y.
        for (int t = 1; t <= 29; t += 2) {
            issue_pair(4 * t + 5 + pw, Ya0, Ya1, Yb0, Yb1);
            VMWAIT28();                                   // retires X's 28 loads
            conv_pair(4 * t + 1 + pw, Xa0, Xa1, Xb0, Xb1);
            LGKM0(); block_sync();

            issue_pair(4 * t + 9 + pw, Xa0, Xa1, Xb0, Xb1);
            VMWAIT28();                                   // retires Y's 28 loads
            conv_pair(4 * t + 5 + pw, Ya0, Ya1, Yb0, Yb1);
            LGKM0(); block_sync();
        }
        // Tick 31: no issue; drain and publish panes 125..128 (buf X).
        VMWAIT0();
        conv_pair(125 + pw, Xa0, Xa1, Xb0, Xb1);
        LGKM0(); block_sync();
        // Producers done (32 barriers incl. B0, matching consumer).
    } else {
        // ================= CONSUMER (pure DP chain) ==========================
        // Relabeled decode: pair o = yp*11 + y.
        const int y0 = l % TT,   yp0 = l / TT;
        const int y1 = o1c % TT, yp1 = o1c / TT;
        const int i0w = y0 * GS + yp0;                    // group y, position yp
        const int i1w = val1 ? (y1 * GS + yp1) : (220 + (l - 57));

        if (l < TT) sp[l * GS + 11] = 0.0f;               // zero pad for b128 phase-2

        const int mb = mask[b];

        float W0[KK], W1[KK];
#pragma unroll
        for (int k = 0; k < KK; ++k) { W0[k] = 0.0f; W1[k] = 0.0f; }
        W0[KK - 1] = (yp0 == TT - 1) ? 1.0f : 0.0f;
        W1[KK - 1] = (val1 && yp1 == TT - 1) ? 1.0f : 0.0f;

        float Cc = 0.0f;
        float savedS = 1.0f;                              // SB snapshot at i==mb
        float savedC = 0.0f;                              // Cc snapshot at i==mb

        __builtin_amdgcn_s_setprio(1);
        block_sync();                                     // B0: panes 1..4 ready

        auto body = [&](int i, const float4& ea0, const float4& ea1,
                               const float4& eb0, const float4& eb1) {
            // ---- phase 1: 7 FMAs per pair (tree), sp write ----
            float p0 = fmaf(ea0.x, W0[0], ea0.y * W0[1]);
            float q0 = fmaf(ea0.z, W0[2], ea0.w * W0[3]);
            float u0 = fmaf(ea1.x, W0[4], ea1.y * W0[5]);
            float s0 = (p0 + q0) + fmaf(ea1.z, W0[6], u0);
            float p1 = fmaf(eb0.x, W1[0], eb0.y * W1[1]);
            float q1 = fmaf(eb0.z, W1[2], eb0.w * W1[3]);
            float u1 = fmaf(eb1.x, W1[4], eb1.y * W1[5]);
            float s1 = (p1 + q1) + fmaf(eb1.z, W1[6], u1);
            sp[i0w] = s0;
            sp[i1w] = s1;

            cfence();                  // DS pipe in-order per wave

            // ---- phase 2 reads (chain-critical) ----
            const float4 qa0 = *(const float4*)(sp + yp0 * GS);
            const float4 qb0 = *(const float4*)(sp + yp0 * GS + 4);
            const float4 qc0 = *(const float4*)(sp + yp0 * GS + 8);
            const float4 qa1 = *(const float4*)(sp + yp1 * GS);
            const float4 qb1 = *(const float4*)(sp + yp1 * GS + 4);
            const float4 qc1 = *(const float4*)(sp + yp1 * GS + 8);

            // ---- phase-2 sums: SA = S(yp0), SB = S(yp1) ----
            const float SA = (((qa0.x + qa0.y) + (qa0.z + qa0.w)) +
                              ((qb0.x + qb0.y) + (qb0.z + qb0.w))) +
                             ((qc0.x + qc0.y) + (qc0.z + qc0.w));
            const float SB = (((qa1.x + qa1.y) + (qa1.z + qa1.w)) +
                              ((qb1.x + qb1.y) + (qb1.z + qb1.w))) +
                             ((qc1.x + qc1.y) + (qc1.z + qc1.w));

            // ---- rescale: r = 1/S(0) (lane 0: yp0 == 0) ----
            const float s0u = rfl(SA);
            const float r = fast_rcp(s0u);

            // snapshot for the final readout (single log2 at kernel end)
            savedS = (i == mb) ? SB : savedS;
            savedC = (i == mb) ? Cc : savedC;
            Cc += fast_log2(s0u);                         // off-chain

#pragma unroll
            for (int k = 0; k < KK - 1; ++k) { W0[k] = W0[k + 1] * r; W1[k] = W1[k + 1] * r; }
            W0[KK - 1] = SA * r;
            W1[KK - 1] = SB * r;

            cfence();                  // order phase-2 reads before next sp writes
        };

        for (int t = 1; t <= 32; ++t) {
            const int p0 = 4 * t - 3;

            // E for steps 1-2 of this tick (8x b128, conflict-free stride-16).
            const float4* r0 = (const float4*)&ring[p0 & (NSLOT - 1)][0];
            const float4* r1 = (const float4*)&ring[(p0 + 1) & (NSLOT - 1)][0];
            const float4 Aa0 = r0[l], Aa1 = r0[128 + l];
            const float4 Ab0 = r0[64 + l], Ab1 = r0[192 + l];
            const float4 Ba0 = r1[l], Ba1 = r1[128 + l];
            const float4 Bb0 = r1[64 + l], Bb1 = r1[192 + l];

            body(p0, Aa0, Aa1, Ab0, Ab1);

            // E for steps 3-4 (issued one full step before first use).
            const float4* r2 = (const float4*)&ring[(p0 + 2) & (NSLOT - 1)][0];
            const float4* r3 = (const float4*)&ring[(p0 + 3) & (NSLOT - 1)][0];
            const float4 Ca0 = r2[l], Ca1 = r2[128 + l];
            const float4 Cb0 = r2[64 + l], Cb1 = r2[192 + l];
            const float4 Da0 = r3[l], Da1 = r3[128 + l];
            const float4 Db0 = r3[64 + l], Db1 = r3[192 + l];

            body(p0 + 1, Ba0, Ba1, Bb0, Bb1);
            body(p0 + 2, Ca0, Ca1, Cb0, Cb1);
            body(p0 + 3, Da0, Da1, Db0, Db1);

            if (t < 32) block_sync();  // 31 tick barriers (+B0 = 32, matches producers)
        }

        if (l == 35) {                 // o1 = 99 -> (yp1=9): row 9 = stop_id
            atomicAdd(out, (savedC + fast_log2(savedS)) * LN2);
        }
    }
}

extern "C" void kernel_launch(void* const* d_in, const int* in_sizes, int n_in,
                              void* d_out, int out_size, void* d_ws, size_t ws_size,
                              hipStream_t stream) {
    const float* scores = (const float*)d_in[0];
    const int*   mask   = (const int*)d_in[1];
    float* out = (float*)d_out;
    const int B = in_sizes[1];   // 16

    hipMemsetAsync(out, 0, sizeof(float) * out_size, stream);

    (void)d_ws; (void)ws_size;   // unused (ws poison is unconditional harness cost)

    hscrf_pc3<<<B, 192, 0, stream>>>(scores, mask, out, B);
}